// Round 12
// baseline (142.812 us; speedup 1.0000x reference)
//
#include <hip/hip_runtime.h>
#include <math.h>

#define NROWS 16384
#define DT_C 0.01f

typedef short s16x8 __attribute__((ext_vector_type(8)));
typedef float f32x4 __attribute__((ext_vector_type(4)));
typedef float f32x2 __attribute__((ext_vector_type(2)));

__device__ __forceinline__ unsigned short f2bf(float f) {
    unsigned u = __float_as_uint(f);
    u += 0x7fffu + ((u >> 16) & 1u);
    return (unsigned short)(u >> 16);
}
__device__ __forceinline__ unsigned pack2bf(float a, float b) {
    return (unsigned)f2bf(a) | ((unsigned)f2bf(b) << 16);
}
// VALU-pipe cross-lane adds via DPP (no LDS pipe).
// sum8: xor1 (0xB1), xor2 (0x4E), row_half_mirror (0x141).
template <int CTRL>
__device__ __forceinline__ float dppadd(float v) {
    int x = __builtin_amdgcn_update_dpp(0, __float_as_int(v), CTRL, 0xF, 0xF, true);
    return v + __int_as_float(x);
}
__device__ __forceinline__ float sum8(float p) {
    p = dppadd<0xB1>(p);
    p = dppadd<0x4E>(p);
    p = dppadd<0x141>(p);
    return p;
}

// ---------------------------------------------------------------------------
// Prep: pack stage-B weights to bf16 flat [stage][k8][n][8] (k = k8*8+j).
// s=0: W_feat1[0:256], s=1: W_feat2, s=2: [W_xim1 | W_xil1].
// ---------------------------------------------------------------------------
__global__ __launch_bounds__(256) void prep_k(
    const float* __restrict__ Wf1, const float* __restrict__ Wf2,
    const float* __restrict__ Wm1, const float* __restrict__ Wl1,
    const float* __restrict__ bm1, const float* __restrict__ bl1,
    unsigned short* __restrict__ wpack, float* __restrict__ biasH)
{
    const int id = blockIdx.x * 256 + threadIdx.x;   // 0..24575
    const int n  = id & 255;
    const int k8 = (id >> 8) & 31;
    const int s  = id >> 13;

    unsigned short tmp[8];
    #pragma unroll
    for (int j = 0; j < 8; ++j) {
        const int k = k8 * 8 + j;
        float v;
        if (s == 0)      v = Wf1[k * 256 + n];
        else if (s == 1) v = Wf2[k * 256 + n];
        else             v = (n < 128) ? Wm1[k * 128 + n] : Wl1[k * 128 + n - 128];
        tmp[j] = f2bf(v);
    }
    *(uint4*)&wpack[((s * 32 + k8) * 256 + n) * 8] = *(const uint4*)tmp;

    if (id < 256) biasH[id] = (id < 128) ? bm1[id] : bl1[id - 128];
}

// ---------------------------------------------------------------------------
// Fused kernel, 512 threads (8 waves) per 64-row block, grid 256 (1 block/CU):
//   stage data->LDS frags (M=64); MFMA h1->feat->heads — 8 waves x 32 cols
//   (acc[4][2]; B-panels read once per block); 128-dots -> xi;
//   then waves 4-7 RETURN and waves 0-3 run the ODE scan with TWO-ROW
//   INTERLEAVE: 8 lanes/row, each 8-lane group owns rows (g, g+8) and steps
//   them alternately — two independent dependency chains per instruction
//   stream hide the partial->sum8->ynext latency. Decay fused, single write.
// ---------------------------------------------------------------------------
__global__ __launch_bounds__(512, 2) void fused_k(
    const float* __restrict__ data, const float* __restrict__ omega,
    const float* __restrict__ eps_g,
    const unsigned short* __restrict__ wpack, const float* __restrict__ biasH,
    const float* __restrict__ bf1, const float* __restrict__ bf2,
    const float* __restrict__ w256g,
    const float* __restrict__ Wm2, const float* __restrict__ bm2,
    const float* __restrict__ Wl2, const float* __restrict__ bl2,
    const float* __restrict__ Wa1, const float* __restrict__ ba1,
    const float* __restrict__ Wa2, const float* __restrict__ ba2,
    float* __restrict__ out_mean, float* __restrict__ out_lnvar,
    float* __restrict__ xout)
{
    // 64.5KB LDS: headsF (64KB) aliases As1+Hs (dead by heads phase)
    __shared__ __align__(16) unsigned char smem[66048];
    unsigned short* As1 = (unsigned short*)smem;            // 32KB frags: data, then feat
    unsigned short* Hs  = (unsigned short*)(smem + 32768);  // 32KB frags: h1
    float* headsF = (float*)smem;                           // 64KB alias: heads f32
    float* omg = (float*)(smem + 65536);                    // [64]
    float* xiS = (float*)(smem + 65792);                    // [64]

    const int tid  = threadIdx.x;
    const int wid  = tid >> 6;          // 0..7
    const int lane = tid & 63;
    const int ln   = lane & 15;
    const int quad = lane >> 4;
    const int r0   = blockIdx.x * 64;

    // ---- stage data -> As1 (coalesced, swizzled frag pack), 64 rows
    {
        #pragma unroll
        for (int g2 = 0; g2 < 8; ++g2) {
            const int unit = g2 * 512 + tid;     // 16B unit over 64x256 f32
            const int m    = unit >> 6;          // row 0..63
            const int c16  = unit & 63;
            const int kblk = c16 >> 1;
            const int h    = c16 & 1;
            const float4 v = *(const float4*)&data[(size_t)(r0 + m) * 256 + c16 * 4];
            unsigned* d = (unsigned*)&As1[((kblk * 64) + (m ^ (kblk & 7))) * 8 + h * 4];
            d[0] = pack2bf(v.x, v.y);
            d[1] = pack2bf(v.z, v.w);
        }
        if (tid < 64) omg[tid] = omega[r0 + tid];
    }
    __syncthreads();                               // B0: As1 + omg ready

    // ---- MFMA phases: 8 waves x 32 cols (2 n-tiles), M=64 (4 m-tiles)
    f32x4 acc[4][2];

    auto seed = [&](const float* bias) {
        #pragma unroll
        for (int nt = 0; nt < 2; ++nt) {
            const float b = bias[wid * 32 + nt * 16 + ln];
            #pragma unroll
            for (int mt = 0; mt < 4; ++mt) acc[mt][nt] = f32x4{b, b, b, b};
        }
    };

    // A-frags from LDS, B-frags straight from global (L2-resident; each
    // column panel read once per block)
    auto run_stage = [&](const unsigned short* Ap, const unsigned short* wp) {
        #pragma unroll
        for (int c = 0; c < 4; ++c) {
            #pragma unroll
            for (int kk = 0; kk < 2; ++kk) {
                const int kb   = kk * 4 + quad;
                const int kblk = c * 8 + kb;
                const int f    = kblk & 7;
                s16x8 b0 = *(const s16x8*)&wp[((size_t)(kblk * 256) + wid * 32 + 0 * 16 + ln) * 8];
                s16x8 b1 = *(const s16x8*)&wp[((size_t)(kblk * 256) + wid * 32 + 1 * 16 + ln) * 8];
                #pragma unroll
                for (int mt = 0; mt < 4; ++mt) {
                    s16x8 a = *(const s16x8*)&Ap[((size_t)kblk * 64 + ((ln ^ f) + 16 * mt)) * 8];
                    acc[mt][0] = __builtin_amdgcn_mfma_f32_16x16x32_bf16(a, b0, acc[mt][0], 0, 0, 0);
                    acc[mt][1] = __builtin_amdgcn_mfma_f32_16x16x32_bf16(a, b1, acc[mt][1], 0, 0, 0);
                }
            }
        }
    };

    auto write_packed = [&](unsigned short* dst, bool addOm) {
        #pragma unroll
        for (int nt = 0; nt < 2; ++nt) {
            const int col = wid * 32 + nt * 16 + ln;
            const int kg  = col >> 3, f = kg & 7, jj = col & 7;
            const float wo = addOm ? w256g[col] : 0.f;
            #pragma unroll
            for (int mt = 0; mt < 4; ++mt) {
                #pragma unroll
                for (int r = 0; r < 4; ++r) {
                    const int row = mt * 16 + quad * 4 + r;
                    float v = acc[mt][nt][r];
                    if (addOm) v = fmaf(omg[row], wo, v);
                    v = fmaxf(v, 0.f);
                    dst[(kg * 64 + (row ^ f)) * 8 + jj] = f2bf(v);
                }
            }
        }
    };

    seed(bf1);
    run_stage(As1, wpack);
    write_packed(Hs, true);
    __syncthreads();                               // B1: Hs ready
    seed(bf2);
    run_stage(Hs, wpack + 65536);
    write_packed(As1, false);
    __syncthreads();                               // B2: As1(feat) ready
    seed(biasH);
    run_stage(As1, wpack + 131072);
    __syncthreads();                               // B3a: all waves done with As1/Hs (alias!)
    #pragma unroll
    for (int nt = 0; nt < 2; ++nt) {
        const int col = wid * 32 + nt * 16 + ln;
        #pragma unroll
        for (int mt = 0; mt < 4; ++mt) {
            #pragma unroll
            for (int r = 0; r < 4; ++r) {
                const int row = mt * 16 + quad * 4 + r;
                headsF[row * 256 + ((col + row * 8) & 255)] = fmaxf(acc[mt][nt][r], 0.f);
            }
        }
    }
    __syncthreads();                               // B3: heads ready

    // ---- 128-dot heads: 8 lanes/row, 64 rows -> xi
    {
        const int m = tid >> 3, l = tid & 7;
        float pm = 0.f, pl = 0.f;
        #pragma unroll
        for (int q = 0; q < 4; ++q) {
            const int c0 = l * 16 + q * 4;
            const float4 hm = *(const float4*)&headsF[m * 256 + ((c0 + m * 8) & 255)];
            const float4 wm = *(const float4*)&Wm2[c0];
            const float4 hl = *(const float4*)&headsF[m * 256 + ((128 + c0 + m * 8) & 255)];
            const float4 wl = *(const float4*)&Wl2[c0];
            pm = fmaf(hm.w, wm.w, fmaf(hm.z, wm.z, fmaf(hm.y, wm.y, fmaf(hm.x, wm.x, pm))));
            pl = fmaf(hl.w, wl.w, fmaf(hl.z, wl.z, fmaf(hl.y, wl.y, fmaf(hl.x, wl.x, pl))));
        }
        pm = sum8(pm);
        pl = sum8(pl);
        if (l == 0) {
            const float xm  = pm + bm2[0];
            const float mean = fmaxf(xm, 0.f) + log1pf(expf(-fabsf(xm)));
            const float lnv  = pl + bl2[0];
            out_mean[r0 + m]  = mean;
            out_lnvar[r0 + m] = lnv;
            float xi = mean + expf(0.5f * lnv) * eps_g[r0 + m];
            xiS[m] = fminf(fmaxf(xi, 0.f), 1.f);
        }
    }
    __syncthreads();                               // B4: xiS ready (LAST barrier)

    // ---- waves 4-7 done; waves 0-3 scan with 2-row interleave.
    if (tid >= 256) return;

    // ODE scan: 8 lanes/row (R0's exact per-row numerics: 8 units/lane,
    // sum8, pipelined pn one step ahead). Each 8-lane group owns TWO rows
    // (rA = w*16+g, rB = w*16+8+g) stepped alternately: two independent
    // dependency chains per instruction stream hide DPP+fma latency.
    // Decay fused into the single xout write.
    {
        const int w  = tid >> 6;         // wave 0..3
        const int g  = (tid & 63) >> 3;  // group 0..7
        const int l  = tid & 7;          // lane in group, units i = l*8..l*8+7
        const int rA = w * 16 + g;
        const int rB = w * 16 + 8 + g;
        const float omA = omg[rA];
        const float omB = omg[rB];
        const float pseed = ba2[0] * 0.125f;

        f32x2 w1v[4], w2v[4], AvA[4], AvB[4];
        #pragma unroll
        for (int i = 0; i < 4; ++i) {
            const f32x2 w0 = *(const f32x2*)&Wa1[l * 8 + i * 2];
            const f32x2 bb = *(const f32x2*)&ba1[l * 8 + i * 2];
            w1v[i] = *(const f32x2*)&Wa1[64 + l * 8 + i * 2];
            w2v[i] = *(const f32x2*)&Wa2[l * 8 + i * 2];
            AvA[i] = f32x2{fmaf(omA, w0.x, bb.x), fmaf(omA, w0.y, bb.y)};
            AvB[i] = f32x2{fmaf(omB, w0.x, bb.x), fmaf(omB, w0.y, bb.y)};
        }

        auto partial = [&](float y, const f32x2* Av) -> float {
            const f32x2 y2 = f32x2{y, y};
            f32x2 acc2 = f32x2{pseed, 0.f};
            #pragma unroll
            for (int i = 0; i < 4; ++i) {
                f32x2 h = __builtin_elementwise_fma(y2, w1v[i], Av[i]);
                h = __builtin_elementwise_max(h, f32x2{0.f, 0.f});
                acc2 = __builtin_elementwise_fma(h, w2v[i], acc2);
            }
            return acc2.x + acc2.y;
        };

        const float DT2 = DT_C * DT_C;
        const float dfacA = expf(-xiS[rA] * DT_C);
        const float dfacB = expf(-xiS[rB] * DT_C);
        const float y0A = data[(size_t)(r0 + rA) * 256];
        const float y0B = data[(size_t)(r0 + rB) * 256];
        float ymA = y0A, ycA = y0A, dA = 1.f;
        float ymB = y0B, ycB = y0B, dB = 1.f;
        float prA = sum8(partial(ymA, AvA));
        float prB = sum8(partial(ymB, AvB));

        float* orowA = xout + (size_t)(r0 + rA) * 256 + l * 4;
        float* orowB = xout + (size_t)(r0 + rB) * 256 + l * 4;
        for (int tb = 0; tb < 8; ++tb) {
            float curA[4], curB[4];
            #pragma unroll
            for (int j = 0; j < 32; ++j) {
                if ((j >> 2) == l) {
                    curA[j & 3] = ymA * dA;        // compile-time index
                    curB[j & 3] = ymB * dB;
                }
                float pnA = partial(ycA, AvA);     // independent chains:
                float pnB = partial(ycB, AvB);     // A and B interleave
                pnA = sum8(pnA);
                pnB = sum8(pnB);
                const float ynA = fmaf(DT2, prA, fmaf(2.f, ycA, -ymA));
                const float ynB = fmaf(DT2, prB, fmaf(2.f, ycB, -ymB));
                ymA = ycA; ycA = ynA; prA = pnA; dA *= dfacA;
                ymB = ycB; ycB = ynB; prB = pnB; dB *= dfacB;
            }
            *(float4*)&orowA[tb * 32] = *(const float4*)curA;
            *(float4*)&orowB[tb * 32] = *(const float4*)curB;
        }
    }
}

// ---------------------------------------------------------------------------
extern "C" void kernel_launch(void* const* d_in, const int* in_sizes, int n_in,
                              void* d_out, int out_size, void* d_ws, size_t ws_size,
                              hipStream_t stream)
{
    const float* data    = (const float*)d_in[0];
    const float* omega   = (const float*)d_in[1];
    const float* eps     = (const float*)d_in[2];
    const float* W_feat1 = (const float*)d_in[3];
    const float* b_feat1 = (const float*)d_in[4];
    const float* W_feat2 = (const float*)d_in[5];
    const float* b_feat2 = (const float*)d_in[6];
    const float* W_xim1  = (const float*)d_in[7];
    const float* b_xim1  = (const float*)d_in[8];
    const float* W_xim2  = (const float*)d_in[9];
    const float* b_xim2  = (const float*)d_in[10];
    const float* W_xil1  = (const float*)d_in[11];
    const float* b_xil1  = (const float*)d_in[12];
    const float* W_xil2  = (const float*)d_in[13];
    const float* b_xil2  = (const float*)d_in[14];
    const float* W_aux1  = (const float*)d_in[15];
    const float* b_aux1  = (const float*)d_in[16];
    const float* W_aux2  = (const float*)d_in[17];
    const float* b_aux2  = (const float*)d_in[18];

    float* out_mean  = (float*)d_out;
    float* out_lnvar = out_mean + NROWS;
    float* out_x     = out_lnvar + NROWS;

    unsigned short* wpack = (unsigned short*)d_ws;           // 384KB bf16
    float* biasH = (float*)((char*)d_ws + 3 * 32 * 256 * 8 * 2);

    prep_k<<<96, 256, 0, stream>>>(W_feat1, W_feat2, W_xim1, W_xil1,
                                   b_xim1, b_xil1, wpack, biasH);
    fused_k<<<256, 512, 0, stream>>>(data, omega, eps, wpack, biasH,
                                     b_feat1, b_feat2, W_feat1 + 256 * 256,
                                     W_xim2, b_xim2, W_xil2, b_xil2,
                                     W_aux1, b_aux1, W_aux2, b_aux2,
                                     out_mean, out_lnvar, out_x);
}

// Round 13
// 138.676 us; speedup vs baseline: 1.0298x; 1.0298x over previous
//
#include <hip/hip_runtime.h>
#include <math.h>

#define NROWS 16384
#define DT_C 0.01f

typedef short s16x8 __attribute__((ext_vector_type(8)));
typedef float f32x4 __attribute__((ext_vector_type(4)));
typedef float f32x2 __attribute__((ext_vector_type(2)));

__device__ __forceinline__ unsigned short f2bf(float f) {
    unsigned u = __float_as_uint(f);
    u += 0x7fffu + ((u >> 16) & 1u);
    return (unsigned short)(u >> 16);
}
__device__ __forceinline__ unsigned pack2bf(float a, float b) {
    return (unsigned)f2bf(a) | ((unsigned)f2bf(b) << 16);
}
// VALU-pipe cross-lane adds via DPP (no LDS pipe).
// sum8: xor1 (0xB1), xor2 (0x4E), row_half_mirror (0x141).
template <int CTRL>
__device__ __forceinline__ float dppadd(float v) {
    int x = __builtin_amdgcn_update_dpp(0, __float_as_int(v), CTRL, 0xF, 0xF, true);
    return v + __int_as_float(x);
}
__device__ __forceinline__ float sum8(float p) {
    p = dppadd<0xB1>(p);
    p = dppadd<0x4E>(p);
    p = dppadd<0x141>(p);
    return p;
}

// ---------------------------------------------------------------------------
// Prep: pack stage-B weights to bf16 flat [stage][k8][n][8] (k = k8*8+j).
// s=0: W_feat1[0:256], s=1: W_feat2, s=2: [W_xim1 | W_xil1].
// ---------------------------------------------------------------------------
__global__ __launch_bounds__(256) void prep_k(
    const float* __restrict__ Wf1, const float* __restrict__ Wf2,
    const float* __restrict__ Wm1, const float* __restrict__ Wl1,
    const float* __restrict__ bm1, const float* __restrict__ bl1,
    unsigned short* __restrict__ wpack, float* __restrict__ biasH)
{
    const int id = blockIdx.x * 256 + threadIdx.x;   // 0..24575
    const int n  = id & 255;
    const int k8 = (id >> 8) & 31;
    const int s  = id >> 13;

    unsigned short tmp[8];
    #pragma unroll
    for (int j = 0; j < 8; ++j) {
        const int k = k8 * 8 + j;
        float v;
        if (s == 0)      v = Wf1[k * 256 + n];
        else if (s == 1) v = Wf2[k * 256 + n];
        else             v = (n < 128) ? Wm1[k * 128 + n] : Wl1[k * 128 + n - 128];
        tmp[j] = f2bf(v);
    }
    *(uint4*)&wpack[((s * 32 + k8) * 256 + n) * 8] = *(const uint4*)tmp;

    if (id < 256) biasH[id] = (id < 128) ? bm1[id] : bl1[id - 128];
}

// ---------------------------------------------------------------------------
// Fused kernel, 512 threads (8 waves) per 64-row block, grid 256 (1 block/CU):
//   stage data->LDS frags (M=64); MFMA h1->feat->heads — 8 waves x 32 cols
//   (acc[4][2]; B-panels read once per block); 128-dots -> xi;
//   then ALL 8 WAVES scan at 8 lanes/row (2 waves/SIMD: hardware round-robin
//   between two resident waves hides the partial->sum8->ynext dependency
//   stall that 1 wave/SIMD could not). R0's proven per-row numerics; decay
//   fused into the single xout write.
// ---------------------------------------------------------------------------
__global__ __launch_bounds__(512, 2) void fused_k(
    const float* __restrict__ data, const float* __restrict__ omega,
    const float* __restrict__ eps_g,
    const unsigned short* __restrict__ wpack, const float* __restrict__ biasH,
    const float* __restrict__ bf1, const float* __restrict__ bf2,
    const float* __restrict__ w256g,
    const float* __restrict__ Wm2, const float* __restrict__ bm2,
    const float* __restrict__ Wl2, const float* __restrict__ bl2,
    const float* __restrict__ Wa1, const float* __restrict__ ba1,
    const float* __restrict__ Wa2, const float* __restrict__ ba2,
    float* __restrict__ out_mean, float* __restrict__ out_lnvar,
    float* __restrict__ xout)
{
    // 64.5KB LDS: headsF (64KB) aliases As1+Hs (dead by heads phase)
    __shared__ __align__(16) unsigned char smem[66048];
    unsigned short* As1 = (unsigned short*)smem;            // 32KB frags: data, then feat
    unsigned short* Hs  = (unsigned short*)(smem + 32768);  // 32KB frags: h1
    float* headsF = (float*)smem;                           // 64KB alias: heads f32
    float* omg = (float*)(smem + 65536);                    // [64]
    float* xiS = (float*)(smem + 65792);                    // [64]

    const int tid  = threadIdx.x;
    const int wid  = tid >> 6;          // 0..7
    const int lane = tid & 63;
    const int ln   = lane & 15;
    const int quad = lane >> 4;
    const int r0   = blockIdx.x * 64;

    // ---- stage data -> As1 (coalesced, swizzled frag pack), 64 rows
    {
        #pragma unroll
        for (int g2 = 0; g2 < 8; ++g2) {
            const int unit = g2 * 512 + tid;     // 16B unit over 64x256 f32
            const int m    = unit >> 6;          // row 0..63
            const int c16  = unit & 63;
            const int kblk = c16 >> 1;
            const int h    = c16 & 1;
            const float4 v = *(const float4*)&data[(size_t)(r0 + m) * 256 + c16 * 4];
            unsigned* d = (unsigned*)&As1[((kblk * 64) + (m ^ (kblk & 7))) * 8 + h * 4];
            d[0] = pack2bf(v.x, v.y);
            d[1] = pack2bf(v.z, v.w);
        }
        if (tid < 64) omg[tid] = omega[r0 + tid];
    }
    __syncthreads();                               // B0: As1 + omg ready

    // ---- MFMA phases: 8 waves x 32 cols (2 n-tiles), M=64 (4 m-tiles)
    f32x4 acc[4][2];

    auto seed = [&](const float* bias) {
        #pragma unroll
        for (int nt = 0; nt < 2; ++nt) {
            const float b = bias[wid * 32 + nt * 16 + ln];
            #pragma unroll
            for (int mt = 0; mt < 4; ++mt) acc[mt][nt] = f32x4{b, b, b, b};
        }
    };

    // A-frags from LDS, B-frags straight from global (L2-resident; each
    // column panel read once per block)
    auto run_stage = [&](const unsigned short* Ap, const unsigned short* wp) {
        #pragma unroll
        for (int c = 0; c < 4; ++c) {
            #pragma unroll
            for (int kk = 0; kk < 2; ++kk) {
                const int kb   = kk * 4 + quad;
                const int kblk = c * 8 + kb;
                const int f    = kblk & 7;
                s16x8 b0 = *(const s16x8*)&wp[((size_t)(kblk * 256) + wid * 32 + 0 * 16 + ln) * 8];
                s16x8 b1 = *(const s16x8*)&wp[((size_t)(kblk * 256) + wid * 32 + 1 * 16 + ln) * 8];
                #pragma unroll
                for (int mt = 0; mt < 4; ++mt) {
                    s16x8 a = *(const s16x8*)&Ap[((size_t)kblk * 64 + ((ln ^ f) + 16 * mt)) * 8];
                    acc[mt][0] = __builtin_amdgcn_mfma_f32_16x16x32_bf16(a, b0, acc[mt][0], 0, 0, 0);
                    acc[mt][1] = __builtin_amdgcn_mfma_f32_16x16x32_bf16(a, b1, acc[mt][1], 0, 0, 0);
                }
            }
        }
    };

    auto write_packed = [&](unsigned short* dst, bool addOm) {
        #pragma unroll
        for (int nt = 0; nt < 2; ++nt) {
            const int col = wid * 32 + nt * 16 + ln;
            const int kg  = col >> 3, f = kg & 7, jj = col & 7;
            const float wo = addOm ? w256g[col] : 0.f;
            #pragma unroll
            for (int mt = 0; mt < 4; ++mt) {
                #pragma unroll
                for (int r = 0; r < 4; ++r) {
                    const int row = mt * 16 + quad * 4 + r;
                    float v = acc[mt][nt][r];
                    if (addOm) v = fmaf(omg[row], wo, v);
                    v = fmaxf(v, 0.f);
                    dst[(kg * 64 + (row ^ f)) * 8 + jj] = f2bf(v);
                }
            }
        }
    };

    seed(bf1);
    run_stage(As1, wpack);
    write_packed(Hs, true);
    __syncthreads();                               // B1: Hs ready
    seed(bf2);
    run_stage(Hs, wpack + 65536);
    write_packed(As1, false);
    __syncthreads();                               // B2: As1(feat) ready
    seed(biasH);
    run_stage(As1, wpack + 131072);
    __syncthreads();                               // B3a: all waves done with As1/Hs (alias!)
    #pragma unroll
    for (int nt = 0; nt < 2; ++nt) {
        const int col = wid * 32 + nt * 16 + ln;
        #pragma unroll
        for (int mt = 0; mt < 4; ++mt) {
            #pragma unroll
            for (int r = 0; r < 4; ++r) {
                const int row = mt * 16 + quad * 4 + r;
                headsF[row * 256 + ((col + row * 8) & 255)] = fmaxf(acc[mt][nt][r], 0.f);
            }
        }
    }
    __syncthreads();                               // B3: heads ready

    // ---- 128-dot heads: 8 lanes/row, 64 rows -> xi
    {
        const int m = tid >> 3, l = tid & 7;
        float pm = 0.f, pl = 0.f;
        #pragma unroll
        for (int q = 0; q < 4; ++q) {
            const int c0 = l * 16 + q * 4;
            const float4 hm = *(const float4*)&headsF[m * 256 + ((c0 + m * 8) & 255)];
            const float4 wm = *(const float4*)&Wm2[c0];
            const float4 hl = *(const float4*)&headsF[m * 256 + ((128 + c0 + m * 8) & 255)];
            const float4 wl = *(const float4*)&Wl2[c0];
            pm = fmaf(hm.w, wm.w, fmaf(hm.z, wm.z, fmaf(hm.y, wm.y, fmaf(hm.x, wm.x, pm))));
            pl = fmaf(hl.w, wl.w, fmaf(hl.z, wl.z, fmaf(hl.y, wl.y, fmaf(hl.x, wl.x, pl))));
        }
        pm = sum8(pm);
        pl = sum8(pl);
        if (l == 0) {
            const float xm  = pm + bm2[0];
            const float mean = fmaxf(xm, 0.f) + log1pf(expf(-fabsf(xm)));
            const float lnv  = pl + bl2[0];
            out_mean[r0 + m]  = mean;
            out_lnvar[r0 + m] = lnv;
            float xi = mean + expf(0.5f * lnv) * eps_g[r0 + m];
            xiS[m] = fminf(fmaxf(xi, 0.f), 1.f);
        }
    }
    __syncthreads();                               // B4: xiS ready (LAST barrier)

    // ---- ODE scan: ALL 8 waves, 8 lanes/row, 64 rows (2 waves/SIMD TLP).
    // R0's proven per-row numerics (8 units/lane, sum8, pn pipelined one
    // step ahead). Decay fused into the single xout write.
    {
        const int r   = tid >> 3;        // row 0..63
        const int l   = tid & 7;         // 8 lanes/row, units i = l*8..l*8+7
        const int row = r0 + r;
        const float om = omg[r];
        const float pseed = ba2[0] * 0.125f;

        f32x2 w1v[4], Av[4], w2v[4];
        #pragma unroll
        for (int i = 0; i < 4; ++i) {
            const f32x2 w0 = *(const f32x2*)&Wa1[l * 8 + i * 2];
            const f32x2 bb = *(const f32x2*)&ba1[l * 8 + i * 2];
            w1v[i] = *(const f32x2*)&Wa1[64 + l * 8 + i * 2];
            w2v[i] = *(const f32x2*)&Wa2[l * 8 + i * 2];
            Av[i]  = f32x2{fmaf(om, w0.x, bb.x), fmaf(om, w0.y, bb.y)};
        }

        auto partial = [&](float y) -> float {
            const f32x2 y2 = f32x2{y, y};
            f32x2 acc2 = f32x2{pseed, 0.f};
            #pragma unroll
            for (int i = 0; i < 4; ++i) {
                f32x2 h = __builtin_elementwise_fma(y2, w1v[i], Av[i]);
                h = __builtin_elementwise_max(h, f32x2{0.f, 0.f});
                acc2 = __builtin_elementwise_fma(h, w2v[i], acc2);
            }
            return acc2.x + acc2.y;
        };

        const float xi   = xiS[r];
        const float dfac = expf(-xi * DT_C);
        const float y0   = data[(size_t)row * 256];
        float ym = y0;          // y_t
        float yc = y0;          // y_{t+1}  (v0 = 0)
        float d  = 1.f;         // dfac^t
        const float DT2 = DT_C * DT_C;
        float pr = sum8(partial(ym));

        float* orow = xout + (size_t)row * 256 + l * 4;
        for (int tb = 0; tb < 8; ++tb) {
            float cur[4];
            #pragma unroll
            for (int j = 0; j < 32; ++j) {
                if ((j >> 2) == l) cur[j & 3] = ym * d;    // y_t * dfac^t
                float pn = sum8(partial(yc));
                const float ynext = fmaf(DT2, pr, fmaf(2.f, yc, -ym));
                ym = yc; yc = ynext; pr = pn;              // pr consumed next step
                d *= dfac;
            }
            *(float4*)&orow[tb * 32] = *(const float4*)cur;
        }
    }
}

// ---------------------------------------------------------------------------
extern "C" void kernel_launch(void* const* d_in, const int* in_sizes, int n_in,
                              void* d_out, int out_size, void* d_ws, size_t ws_size,
                              hipStream_t stream)
{
    const float* data    = (const float*)d_in[0];
    const float* omega   = (const float*)d_in[1];
    const float* eps     = (const float*)d_in[2];
    const float* W_feat1 = (const float*)d_in[3];
    const float* b_feat1 = (const float*)d_in[4];
    const float* W_feat2 = (const float*)d_in[5];
    const float* b_feat2 = (const float*)d_in[6];
    const float* W_xim1  = (const float*)d_in[7];
    const float* b_xim1  = (const float*)d_in[8];
    const float* W_xim2  = (const float*)d_in[9];
    const float* b_xim2  = (const float*)d_in[10];
    const float* W_xil1  = (const float*)d_in[11];
    const float* b_xil1  = (const float*)d_in[12];
    const float* W_xil2  = (const float*)d_in[13];
    const float* b_xil2  = (const float*)d_in[14];
    const float* W_aux1  = (const float*)d_in[15];
    const float* b_aux1  = (const float*)d_in[16];
    const float* W_aux2  = (const float*)d_in[17];
    const float* b_aux2  = (const float*)d_in[18];

    float* out_mean  = (float*)d_out;
    float* out_lnvar = out_mean + NROWS;
    float* out_x     = out_lnvar + NROWS;

    unsigned short* wpack = (unsigned short*)d_ws;           // 384KB bf16
    float* biasH = (float*)((char*)d_ws + 3 * 32 * 256 * 8 * 2);

    prep_k<<<96, 256, 0, stream>>>(W_feat1, W_feat2, W_xim1, W_xil1,
                                   b_xim1, b_xil1, wpack, biasH);
    fused_k<<<256, 512, 0, stream>>>(data, omega, eps, wpack, biasH,
                                     b_feat1, b_feat2, W_feat1 + 256 * 256,
                                     W_xim2, b_xim2, W_xil2, b_xil2,
                                     W_aux1, b_aux1, W_aux2, b_aux2,
                                     out_mean, out_lnvar, out_x);
}

// Round 14
// 137.625 us; speedup vs baseline: 1.0377x; 1.0076x over previous
//
#include <hip/hip_runtime.h>
#include <math.h>

#define NROWS 16384
#define DT_C 0.01f

typedef short s16x8 __attribute__((ext_vector_type(8)));
typedef float f32x4 __attribute__((ext_vector_type(4)));
typedef float f32x2 __attribute__((ext_vector_type(2)));

__device__ __forceinline__ unsigned short f2bf(float f) {
    unsigned u = __float_as_uint(f);
    u += 0x7fffu + ((u >> 16) & 1u);
    return (unsigned short)(u >> 16);
}
__device__ __forceinline__ unsigned pack2bf(float a, float b) {
    return (unsigned)f2bf(a) | ((unsigned)f2bf(b) << 16);
}
// VALU-pipe cross-lane adds via DPP (no LDS pipe).
// sum4: xor1 (quad_perm 0xB1), xor2 (quad_perm 0x4E) — within each 4-lane group.
// sum8: + row_half_mirror (0x141).
template <int CTRL>
__device__ __forceinline__ float dppadd(float v) {
    int x = __builtin_amdgcn_update_dpp(0, __float_as_int(v), CTRL, 0xF, 0xF, true);
    return v + __int_as_float(x);
}
__device__ __forceinline__ float sum4(float p) {
    p = dppadd<0xB1>(p);
    p = dppadd<0x4E>(p);
    return p;
}
__device__ __forceinline__ float sum8(float p) {
    p = dppadd<0xB1>(p);
    p = dppadd<0x4E>(p);
    p = dppadd<0x141>(p);
    return p;
}

// ---------------------------------------------------------------------------
// Prep: pack stage-B weights to bf16 flat [stage][k8][n][8] (k = k8*8+j).
// s=0: W_feat1[0:256], s=1: W_feat2, s=2: [W_xim1 | W_xil1].
// ---------------------------------------------------------------------------
__global__ __launch_bounds__(256) void prep_k(
    const float* __restrict__ Wf1, const float* __restrict__ Wf2,
    const float* __restrict__ Wm1, const float* __restrict__ Wl1,
    const float* __restrict__ bm1, const float* __restrict__ bl1,
    unsigned short* __restrict__ wpack, float* __restrict__ biasH)
{
    const int id = blockIdx.x * 256 + threadIdx.x;   // 0..24575
    const int n  = id & 255;
    const int k8 = (id >> 8) & 31;
    const int s  = id >> 13;

    unsigned short tmp[8];
    #pragma unroll
    for (int j = 0; j < 8; ++j) {
        const int k = k8 * 8 + j;
        float v;
        if (s == 0)      v = Wf1[k * 256 + n];
        else if (s == 1) v = Wf2[k * 256 + n];
        else             v = (n < 128) ? Wm1[k * 128 + n] : Wl1[k * 128 + n - 128];
        tmp[j] = f2bf(v);
    }
    *(uint4*)&wpack[((s * 32 + k8) * 256 + n) * 8] = *(const uint4*)tmp;

    if (id < 256) biasH[id] = (id < 128) ? bm1[id] : bl1[id - 128];
}

// ---------------------------------------------------------------------------
// Fused kernel, 512 threads (8 waves) per 64-row block, grid 256 (1 block/CU):
//   stage data->LDS frags (M=64); MFMA h1->feat->heads — 8 waves x 32 cols
//   (acc[4][2]; B-panels read once per block, half the L2 traffic of 32-row
//   tiles); 128-dots -> xi; then waves 4-7 RETURN and waves 0-3 (one per
//   SIMD) run the ODE scan at 4 lanes/row (16 MLP units/lane, sum4 = 2
//   DPP-adds, split accumulators -> issue-bound at 1 wave/SIMD), decay fused
//   into the single xout write.
// ---------------------------------------------------------------------------
__global__ __launch_bounds__(512, 2) void fused_k(
    const float* __restrict__ data, const float* __restrict__ omega,
    const float* __restrict__ eps_g,
    const unsigned short* __restrict__ wpack, const float* __restrict__ biasH,
    const float* __restrict__ bf1, const float* __restrict__ bf2,
    const float* __restrict__ w256g,
    const float* __restrict__ Wm2, const float* __restrict__ bm2,
    const float* __restrict__ Wl2, const float* __restrict__ bl2,
    const float* __restrict__ Wa1, const float* __restrict__ ba1,
    const float* __restrict__ Wa2, const float* __restrict__ ba2,
    float* __restrict__ out_mean, float* __restrict__ out_lnvar,
    float* __restrict__ xout)
{
    // 64.5KB LDS: headsF (64KB) aliases As1+Hs (dead by heads phase)
    __shared__ __align__(16) unsigned char smem[66048];
    unsigned short* As1 = (unsigned short*)smem;            // 32KB frags: data, then feat
    unsigned short* Hs  = (unsigned short*)(smem + 32768);  // 32KB frags: h1
    float* headsF = (float*)smem;                           // 64KB alias: heads f32
    float* omg = (float*)(smem + 65536);                    // [64]
    float* xiS = (float*)(smem + 65792);                    // [64]

    const int tid  = threadIdx.x;
    const int wid  = tid >> 6;          // 0..7
    const int lane = tid & 63;
    const int ln   = lane & 15;
    const int quad = lane >> 4;
    const int r0   = blockIdx.x * 64;

    // ---- stage data -> As1 (coalesced, swizzled frag pack), 64 rows
    {
        #pragma unroll
        for (int g2 = 0; g2 < 8; ++g2) {
            const int unit = g2 * 512 + tid;     // 16B unit over 64x256 f32
            const int m    = unit >> 6;          // row 0..63
            const int c16  = unit & 63;
            const int kblk = c16 >> 1;
            const int h    = c16 & 1;
            const float4 v = *(const float4*)&data[(size_t)(r0 + m) * 256 + c16 * 4];
            unsigned* d = (unsigned*)&As1[((kblk * 64) + (m ^ (kblk & 7))) * 8 + h * 4];
            d[0] = pack2bf(v.x, v.y);
            d[1] = pack2bf(v.z, v.w);
        }
        if (tid < 64) omg[tid] = omega[r0 + tid];
    }
    __syncthreads();                               // B0: As1 + omg ready

    // ---- MFMA phases: 8 waves x 32 cols (2 n-tiles), M=64 (4 m-tiles)
    f32x4 acc[4][2];

    auto seed = [&](const float* bias) {
        #pragma unroll
        for (int nt = 0; nt < 2; ++nt) {
            const float b = bias[wid * 32 + nt * 16 + ln];
            #pragma unroll
            for (int mt = 0; mt < 4; ++mt) acc[mt][nt] = f32x4{b, b, b, b};
        }
    };

    // A-frags from LDS, B-frags straight from global (L2-resident; each
    // column panel read once per block -> half the L2 traffic of 32-row tiles)
    auto run_stage = [&](const unsigned short* Ap, const unsigned short* wp) {
        #pragma unroll
        for (int c = 0; c < 4; ++c) {
            #pragma unroll
            for (int kk = 0; kk < 2; ++kk) {
                const int kb   = kk * 4 + quad;
                const int kblk = c * 8 + kb;
                const int f    = kblk & 7;
                s16x8 b0 = *(const s16x8*)&wp[((size_t)(kblk * 256) + wid * 32 + 0 * 16 + ln) * 8];
                s16x8 b1 = *(const s16x8*)&wp[((size_t)(kblk * 256) + wid * 32 + 1 * 16 + ln) * 8];
                #pragma unroll
                for (int mt = 0; mt < 4; ++mt) {
                    s16x8 a = *(const s16x8*)&Ap[((size_t)kblk * 64 + ((ln ^ f) + 16 * mt)) * 8];
                    acc[mt][0] = __builtin_amdgcn_mfma_f32_16x16x32_bf16(a, b0, acc[mt][0], 0, 0, 0);
                    acc[mt][1] = __builtin_amdgcn_mfma_f32_16x16x32_bf16(a, b1, acc[mt][1], 0, 0, 0);
                }
            }
        }
    };

    auto write_packed = [&](unsigned short* dst, bool addOm) {
        #pragma unroll
        for (int nt = 0; nt < 2; ++nt) {
            const int col = wid * 32 + nt * 16 + ln;
            const int kg  = col >> 3, f = kg & 7, jj = col & 7;
            const float wo = addOm ? w256g[col] : 0.f;
            #pragma unroll
            for (int mt = 0; mt < 4; ++mt) {
                #pragma unroll
                for (int r = 0; r < 4; ++r) {
                    const int row = mt * 16 + quad * 4 + r;
                    float v = acc[mt][nt][r];
                    if (addOm) v = fmaf(omg[row], wo, v);
                    v = fmaxf(v, 0.f);
                    dst[(kg * 64 + (row ^ f)) * 8 + jj] = f2bf(v);
                }
            }
        }
    };

    seed(bf1);
    run_stage(As1, wpack);
    write_packed(Hs, true);
    __syncthreads();                               // B1: Hs ready
    seed(bf2);
    run_stage(Hs, wpack + 65536);
    write_packed(As1, false);
    __syncthreads();                               // B2: As1(feat) ready
    seed(biasH);
    run_stage(As1, wpack + 131072);
    __syncthreads();                               // B3a: all waves done with As1/Hs (alias!)
    #pragma unroll
    for (int nt = 0; nt < 2; ++nt) {
        const int col = wid * 32 + nt * 16 + ln;
        #pragma unroll
        for (int mt = 0; mt < 4; ++mt) {
            #pragma unroll
            for (int r = 0; r < 4; ++r) {
                const int row = mt * 16 + quad * 4 + r;
                headsF[row * 256 + ((col + row * 8) & 255)] = fmaxf(acc[mt][nt][r], 0.f);
            }
        }
    }
    __syncthreads();                               // B3: heads ready

    // ---- 128-dot heads: 8 lanes/row, 64 rows -> xi
    {
        const int m = tid >> 3, l = tid & 7;
        float pm = 0.f, pl = 0.f;
        #pragma unroll
        for (int q = 0; q < 4; ++q) {
            const int c0 = l * 16 + q * 4;
            const float4 hm = *(const float4*)&headsF[m * 256 + ((c0 + m * 8) & 255)];
            const float4 wm = *(const float4*)&Wm2[c0];
            const float4 hl = *(const float4*)&headsF[m * 256 + ((128 + c0 + m * 8) & 255)];
            const float4 wl = *(const float4*)&Wl2[c0];
            pm = fmaf(hm.w, wm.w, fmaf(hm.z, wm.z, fmaf(hm.y, wm.y, fmaf(hm.x, wm.x, pm))));
            pl = fmaf(hl.w, wl.w, fmaf(hl.z, wl.z, fmaf(hl.y, wl.y, fmaf(hl.x, wl.x, pl))));
        }
        pm = sum8(pm);
        pl = sum8(pl);
        if (l == 0) {
            const float xm  = pm + bm2[0];
            const float mean = fmaxf(xm, 0.f) + log1pf(expf(-fabsf(xm)));
            const float lnv  = pl + bl2[0];
            out_mean[r0 + m]  = mean;
            out_lnvar[r0 + m] = lnv;
            float xi = mean + expf(0.5f * lnv) * eps_g[r0 + m];
            xiS[m] = fminf(fmaxf(xi, 0.f), 1.f);
        }
    }
    __syncthreads();                               // B4: xiS ready (LAST barrier)

    // ---- waves 4-7 done; waves 0-3 (one per SIMD) scan at 4 lanes/row.
    if (tid >= 256) return;

    // ODE scan, R0's proven pipelined recurrence (pn computed one step ahead),
    // 16 MLP units/lane in f32x2 pairs, SPLIT accumulators (shorter dep chain),
    // sum4 = 2 DPP-adds. Decay fused into the single xout write.
    {
        const int r   = tid >> 2;        // row 0..63
        const int l   = tid & 3;         // 4 lanes/row, units i = l*16..l*16+15
        const int row = r0 + r;
        const float om = omg[r];
        const float pseed = ba2[0] * 0.25f;

        f32x2 w1v[8], Av[8], w2v[8];
        #pragma unroll
        for (int i = 0; i < 8; ++i) {
            const f32x2 w0 = *(const f32x2*)&Wa1[l * 16 + i * 2];
            const f32x2 bb = *(const f32x2*)&ba1[l * 16 + i * 2];
            w1v[i] = *(const f32x2*)&Wa1[64 + l * 16 + i * 2];
            w2v[i] = *(const f32x2*)&Wa2[l * 16 + i * 2];
            Av[i]  = f32x2{fmaf(om, w0.x, bb.x), fmaf(om, w0.y, bb.y)};
        }

        auto partial = [&](float y) -> float {
            const f32x2 y2 = f32x2{y, y};
            f32x2 aA = f32x2{pseed, 0.f};
            f32x2 aB = f32x2{0.f, 0.f};
            #pragma unroll
            for (int i = 0; i < 4; ++i) {
                f32x2 h = __builtin_elementwise_fma(y2, w1v[i], Av[i]);
                h = __builtin_elementwise_max(h, f32x2{0.f, 0.f});
                aA = __builtin_elementwise_fma(h, w2v[i], aA);
            }
            #pragma unroll
            for (int i = 4; i < 8; ++i) {
                f32x2 g = __builtin_elementwise_fma(y2, w1v[i], Av[i]);
                g = __builtin_elementwise_max(g, f32x2{0.f, 0.f});
                aB = __builtin_elementwise_fma(g, w2v[i], aB);
            }
            return (aA.x + aA.y) + (aB.x + aB.y);
        };

        const float xi   = xiS[r];
        const float dfac = expf(-xi * DT_C);
        const float y0   = data[(size_t)row * 256];
        float ym = y0;          // y_t
        float yc = y0;          // y_{t+1}  (v0 = 0)
        float d  = 1.f;         // dfac^t
        const float DT2 = DT_C * DT_C;
        float pr = sum4(partial(ym));

        float* orow = xout + (size_t)row * 256 + l * 4;
        for (int tb = 0; tb < 16; ++tb) {
            float cur[4];
            #pragma unroll
            for (int j = 0; j < 16; ++j) {
                if ((j >> 2) == l) cur[j & 3] = ym * d;    // y_t * dfac^t
                float pn = sum4(partial(yc));
                const float ynext = fmaf(DT2, pr, fmaf(2.f, yc, -ym));
                ym = yc; yc = ynext; pr = pn;              // pr consumed next step
                d *= dfac;
            }
            *(float4*)&orow[tb * 16] = *(const float4*)cur;
        }
    }
}

// ---------------------------------------------------------------------------
extern "C" void kernel_launch(void* const* d_in, const int* in_sizes, int n_in,
                              void* d_out, int out_size, void* d_ws, size_t ws_size,
                              hipStream_t stream)
{
    const float* data    = (const float*)d_in[0];
    const float* omega   = (const float*)d_in[1];
    const float* eps     = (const float*)d_in[2];
    const float* W_feat1 = (const float*)d_in[3];
    const float* b_feat1 = (const float*)d_in[4];
    const float* W_feat2 = (const float*)d_in[5];
    const float* b_feat2 = (const float*)d_in[6];
    const float* W_xim1  = (const float*)d_in[7];
    const float* b_xim1  = (const float*)d_in[8];
    const float* W_xim2  = (const float*)d_in[9];
    const float* b_xim2  = (const float*)d_in[10];
    const float* W_xil1  = (const float*)d_in[11];
    const float* b_xil1  = (const float*)d_in[12];
    const float* W_xil2  = (const float*)d_in[13];
    const float* b_xil2  = (const float*)d_in[14];
    const float* W_aux1  = (const float*)d_in[15];
    const float* b_aux1  = (const float*)d_in[16];
    const float* W_aux2  = (const float*)d_in[17];
    const float* b_aux2  = (const float*)d_in[18];

    float* out_mean  = (float*)d_out;
    float* out_lnvar = out_mean + NROWS;
    float* out_x     = out_lnvar + NROWS;

    unsigned short* wpack = (unsigned short*)d_ws;           // 384KB bf16
    float* biasH = (float*)((char*)d_ws + 3 * 32 * 256 * 8 * 2);

    prep_k<<<96, 256, 0, stream>>>(W_feat1, W_feat2, W_xim1, W_xil1,
                                   b_xim1, b_xil1, wpack, biasH);
    fused_k<<<256, 512, 0, stream>>>(data, omega, eps, wpack, biasH,
                                     b_feat1, b_feat2, W_feat1 + 256 * 256,
                                     W_xim2, b_xim2, W_xil2, b_xil2,
                                     W_aux1, b_aux1, W_aux2, b_aux2,
                                     out_mean, out_lnvar, out_x);
}